// Round 15
// baseline (62.749 us; speedup 1.0000x reference)
//
#include <hip/hip_runtime.h>
#include <math.h>

// Problem constants: z [4,32,32,32] f32, embedding [32768,32] f32.
constexpr int Bc   = 4;
constexpr int Dc   = 32;
constexpr int HWc  = 1024;
constexpr int NE   = 32768;
constexpr int POS  = Bc * HWc;        // 4096 positions

constexpr int CCODES = 256;           // codes per chunk (32 KB in LDS)
constexpr int NCHUNK = NE / CCODES;   // 128
constexpr int PPB    = 256;           // positions per phase-A block (8 waves)
constexpr int NPBLK  = POS / PPB;     // 16
constexpr int NPT    = POS / 16;      // 256 pos-tiles of 16

typedef _Float16 f16x8 __attribute__((ext_vector_type(8)));
typedef float    f32x4 __attribute__((ext_vector_type(4)));
typedef unsigned long long u64;

// Monotonic float->uint; pack with ~idx: equal values -> smaller index wins
// under max (== jnp.argmax first-index rule).
__device__ inline unsigned encF(float v) {
    unsigned u = __float_as_uint(v);
    return (u & 0x80000000u) ? ~u : (u | 0x80000000u);
}
__device__ inline u64 packVI(float v, int idx) {
    return ((u64)encF(v) << 32) | (unsigned)(~idx);
}

// Prep: split-fp16 conversion (hi+lo = x to ~2^-22; exact argmax verified
// rounds 8-14). Blocks 0..127: emb -> Es [32768][64]. Blocks 128..143:
// z -> Zs [4096][64], zero best (u32) and best2 (u64).
__global__ __launch_bounds__(256) void vq_eprep(
    const float* __restrict__ emb, const float* __restrict__ z,
    _Float16* __restrict__ Es, _Float16* __restrict__ Zs,
    unsigned* __restrict__ best, u64* __restrict__ best2)
{
    float x[Dc];
    _Float16* dptr;
    if (blockIdx.x < NE / 256) {
        const int c = blockIdx.x * 256 + threadIdx.x;
        const float4* src = reinterpret_cast<const float4*>(emb + (size_t)c * Dc);
#pragma unroll
        for (int q = 0; q < 8; ++q) {
            const float4 v = src[q];
            x[4*q+0] = v.x; x[4*q+1] = v.y; x[4*q+2] = v.z; x[4*q+3] = v.w;
        }
        dptr = Es + (size_t)c * 64;
    } else {
        const int p = (blockIdx.x - NE / 256) * 256 + threadIdx.x;
        best[p]  = 0u;     // below any encoded real
        best2[p] = 0ULL;
        const int b = p >> 10, hw = p & (HWc - 1);
        const float* zp = z + (size_t)b * Dc * HWc + hw;
#pragma unroll
        for (int d = 0; d < Dc; ++d) x[d] = zp[(size_t)d * HWc];
        dptr = Zs + (size_t)p * 64;
    }
    f16x8* dst = reinterpret_cast<f16x8*>(dptr);
#pragma unroll
    for (int q = 0; q < 4; ++q) {
        f16x8 h, l;
#pragma unroll
        for (int r = 0; r < 8; ++r) {
            const float xv = x[8*q+r];
            const _Float16 hv = (_Float16)xv;
            h[r] = hv;
            l[r] = (_Float16)(xv - (float)hv);
        }
        dst[q]     = h;
        dst[4 + q] = l;
    }
}

// Phase A: max VALUE only. Epilogue = 1 fmax-chain op per 2 logits (r14 paid
// 3 VALU/logit -- at the observed effective clock the kernel is issue-bound
// and the epilogue out-issued the MFMAs). Tile-pairs give 2 independent MFMA
// chains. Tail: per-block f32 reduce -> chunkmax[chunk][pos] + u32 atomicMax
// best[pos]. Staging/swizzle identical to r10-r14 (0 conflicts measured).
__global__ __launch_bounds__(512)
__attribute__((amdgpu_waves_per_eu(4, 8)))
void vq_phaseA(
    const _Float16* __restrict__ Zs, const _Float16* __restrict__ Es,
    float* __restrict__ chunkmax, unsigned* __restrict__ best)
{
    __shared__ __align__(16) char lds[CCODES * 128];   // 32 KB

    const int lin  = blockIdx.x;               // 0..2047
    const int xcd  = lin & 7;
    const int j    = lin >> 3;
    const int chunk = xcd * (NCHUNK / 8) + (j & (NCHUNK / 8 - 1));
    const int pblk  = j >> 4;                  // 0..15
    const int tid  = threadIdx.x;
    const int wave = tid >> 6, lane = tid & 63;
    const int m = lane & 15, g = lane >> 4;

    // stage chunk -> LDS (global_load_lds, pre-swizzled source)
    {
        const char* src = (const char*)(Es + (size_t)chunk * CCODES * 64);
        char* dstbase = lds + wave * 1024;
#pragma unroll
        for (int r = 0; r < 4; ++r) {
            const int o    = r * 512 + tid;
            const int row  = o >> 3;
            const int ccol = o & 7;
            const int soff = row * 128 + ((ccol ^ (row & 7)) << 4);
            __builtin_amdgcn_global_load_lds(
                (const __attribute__((address_space(1))) void*)(src + soff),
                (__attribute__((address_space(3))) void*)(dstbase + r * 8192),
                16, 0, 0);
        }
    }

    const int posBase0 = pblk * PPB;
    const int posBase  = posBase0 + wave * 32;
    f16x8 Ahi[2], Alo[2];
#pragma unroll
    for (int t = 0; t < 2; ++t) {
        const _Float16* zrow = Zs + (size_t)(posBase + t * 16 + m) * 64 + 8 * g;
        Ahi[t] = *reinterpret_cast<const f16x8*>(zrow);
        Alo[t] = *reinterpret_cast<const f16x8*>(zrow + 32);
    }
#pragma unroll
    for (int t = 0; t < 2; ++t) asm volatile("" : "+v"(Ahi[t]), "+v"(Alo[t]));

    f32x4 zacc = {0.f, 0.f, 0.f, 0.f};
    asm volatile("" : "+v"(zacc));

    float bval[8];
#pragma unroll
    for (int i = 0; i < 8; ++i) bval[i] = -INFINITY;

    __syncthreads();

    const char* lbase = lds;
    const int off_h = m * 128 + (( g      ^ (m & 7)) << 4);
    const int off_l = m * 128 + (((g + 4) ^ (m & 7)) << 4);

#pragma unroll 2
    for (int ct = 0; ct < CCODES / 16; ct += 2) {      // tile pairs
        const char* p0 = lbase + ct * 2048;
        const f16x8 Bh0 = *reinterpret_cast<const f16x8*>(p0 + off_h);
        const f16x8 Bl0 = *reinterpret_cast<const f16x8*>(p0 + off_l);
        const f16x8 Bh1 = *reinterpret_cast<const f16x8*>(p0 + 2048 + off_h);
        const f16x8 Bl1 = *reinterpret_cast<const f16x8*>(p0 + 2048 + off_l);

#pragma unroll
        for (int t = 0; t < 2; ++t) {
            f32x4 aA, aB;      // two independent chains
            aA = __builtin_amdgcn_mfma_f32_16x16x32_f16(Ahi[t], Bh0, zacc, 0, 0, 0);
            aB = __builtin_amdgcn_mfma_f32_16x16x32_f16(Ahi[t], Bh1, zacc, 0, 0, 0);
            aA = __builtin_amdgcn_mfma_f32_16x16x32_f16(Ahi[t], Bl0, aA,  0, 0, 0);
            aB = __builtin_amdgcn_mfma_f32_16x16x32_f16(Ahi[t], Bl1, aB,  0, 0, 0);
            aA = __builtin_amdgcn_mfma_f32_16x16x32_f16(Alo[t], Bh0, aA,  0, 0, 0);
            aB = __builtin_amdgcn_mfma_f32_16x16x32_f16(Alo[t], Bh1, aB,  0, 0, 0);
#pragma unroll
            for (int r = 0; r < 4; ++r)
                bval[t*4+r] = fmaxf(fmaxf(bval[t*4+r], aA[r]), aB[r]);  // max3
        }
    }

    // tail: value-only reduce across the 16 cols of each position
    __syncthreads();
    float* red = reinterpret_cast<float*>(lds);        // [256][17] f32
#pragma unroll
    for (int i = 0; i < 8; ++i) {
        const int t = i >> 2, r = i & 3;
        const int row = wave * 32 + t * 16 + 4 * g + r;
        red[row * 17 + m] = bval[i];
    }
    __syncthreads();
    if (tid < PPB) {
        float mx = red[tid * 17];
#pragma unroll
        for (int mm = 1; mm < 16; ++mm) mx = fmaxf(mx, red[tid * 17 + mm]);
        chunkmax[(size_t)chunk * POS + posBase0 + tid] = mx;
        atomicMax(best + posBase0 + tid, encF(mx));
    }
}

// Phase B: index recovery. One wave per (chunk, pos-tile); runs only if some
// position's chunkmax equals the global best (expected ~12% of waves; the
// winning chunk always qualifies). Recomputes the chunk's logits with the
// BIT-IDENTICAL MFMA sequence (deterministic), tracks (val, tile), commits
// packed u64 atomics. B read from global Es (L2-hot), no LDS.
__global__ __launch_bounds__(256) void vq_phaseB(
    const _Float16* __restrict__ Zs, const _Float16* __restrict__ Es,
    const float* __restrict__ chunkmax, const unsigned* __restrict__ best,
    u64* __restrict__ best2)
{
    const int gw    = blockIdx.x * 4 + (threadIdx.x >> 6);  // 0..32767
    const int chunk = gw >> 8;                              // 0..127
    const int ptile = gw & 255;                             // 0..255
    const int lane  = threadIdx.x & 63;
    const int m = lane & 15, g = lane >> 4;

    const int posLane = ptile * 16 + m;
    const float cmx   = chunkmax[(size_t)chunk * POS + posLane];
    const bool match  = (lane < 16) && (encF(cmx) == best[posLane]);
    if (!__any(match)) return;

    const _Float16* zrow = Zs + (size_t)posLane * 64 + 8 * g;
    const f16x8 Ahi = *reinterpret_cast<const f16x8*>(zrow);
    const f16x8 Alo = *reinterpret_cast<const f16x8*>(zrow + 32);

    const f32x4 zacc = {0.f, 0.f, 0.f, 0.f};
    const int cbase = chunk * CCODES;
    const char* ebase = (const char*)Es + (size_t)(cbase + m) * 128 + g * 16;

    float bval[4];
    int   bct[4];
#pragma unroll
    for (int r = 0; r < 4; ++r) { bval[r] = -INFINITY; bct[r] = 0; }

#pragma unroll 2
    for (int ct = 0; ct < CCODES / 16; ++ct) {
        const char* ep = ebase + (size_t)ct * 16 * 128;
        const f16x8 Bh = *reinterpret_cast<const f16x8*>(ep);
        const f16x8 Bl = *reinterpret_cast<const f16x8*>(ep + 64);
        f32x4 acc;
        acc = __builtin_amdgcn_mfma_f32_16x16x32_f16(Ahi, Bh, zacc, 0, 0, 0);
        acc = __builtin_amdgcn_mfma_f32_16x16x32_f16(Ahi, Bl, acc,  0, 0, 0);
        acc = __builtin_amdgcn_mfma_f32_16x16x32_f16(Alo, Bh, acc,  0, 0, 0);
#pragma unroll
        for (int r = 0; r < 4; ++r) {
            const bool up = acc[r] > bval[r];     // strict '>': first tile
            bct[r]  = up ? ct : bct[r];
            bval[r] = fmaxf(bval[r], acc[r]);
        }
    }

    u64 pk[4];
#pragma unroll
    for (int r = 0; r < 4; ++r)
        pk[r] = packVI(bval[r], cbase + bct[r] * 16 + m);
#pragma unroll
    for (int s = 1; s < 16; s <<= 1) {
#pragma unroll
        for (int r = 0; r < 4; ++r) {
            const u64 o = __shfl_xor(pk[r], s, 64);
            if (o > pk[r]) pk[r] = o;
        }
    }
    u64 mine = pk[0];
    if (m == 1) mine = pk[1];
    if (m == 2) mine = pk[2];
    if (m == 3) mine = pk[3];
    if (m < 4) atomicMax(best2 + ptile * 16 + 4 * g + m, mine);
}

// Finish: decode winner, gather embedding row, write z_q coalesced + index.
__global__ __launch_bounds__(256) void vq_finish_kernel(
    const u64* __restrict__ best2, const float* __restrict__ emb,
    float* __restrict__ zq, float* __restrict__ indOut)
{
    const int p = blockIdx.x * 256 + threadIdx.x;
    const u64 pk = best2[p];
    const int idx = (int)(~(unsigned)pk);

    const float4* e = reinterpret_cast<const float4*>(emb + (size_t)idx * Dc);
    const int b  = p >> 10;
    const int hw = p & (HWc - 1);
    float* o = zq + (size_t)b * Dc * HWc + hw;
#pragma unroll
    for (int q = 0; q < 8; ++q) {
        const float4 v = e[q];
        o[(size_t)(4*q+0) * HWc] = v.x;
        o[(size_t)(4*q+1) * HWc] = v.y;
        o[(size_t)(4*q+2) * HWc] = v.z;
        o[(size_t)(4*q+3) * HWc] = v.w;
    }
    indOut[p] = (float)idx;
}

extern "C" void kernel_launch(void* const* d_in, const int* in_sizes, int n_in,
                              void* d_out, int out_size, void* d_ws, size_t ws_size,
                              hipStream_t stream)
{
    const float* z   = (const float*)d_in[0];
    const float* emb = (const float*)d_in[1];

    float* out    = (float*)d_out;
    float* zq     = out;
    float* indOut = out + (size_t)Bc * Dc * HWc;

    // ws layout (poison fill showed ws ~256 MB; ample):
    char* w = (char*)d_ws;
    u64*      best2    = (u64*)w;                       w += (size_t)POS * 8;
    unsigned* best     = (unsigned*)w;                  w += (size_t)POS * 4;
    float*    chunkmax = (float*)w;                     w += (size_t)NCHUNK * POS * 4;
    _Float16* Es       = (_Float16*)w;                  w += (size_t)NE * 64 * 2;
    _Float16* Zs       = (_Float16*)w;

    hipLaunchKernelGGL(vq_eprep, dim3(NE / 256 + POS / 256), dim3(256), 0,
                       stream, emb, z, Es, Zs, best, best2);
    hipLaunchKernelGGL(vq_phaseA, dim3(NCHUNK * NPBLK), dim3(512), 0, stream,
                       Zs, Es, chunkmax, best);
    hipLaunchKernelGGL(vq_phaseB, dim3(NCHUNK * NPT / 4), dim3(256), 0, stream,
                       Zs, Es, chunkmax, best, best2);
    hipLaunchKernelGGL(vq_finish_kernel, dim3(POS / 256), dim3(256), 0, stream,
                       best2, emb, zq, indOut);
}

// Round 16
// 50.550 us; speedup vs baseline: 1.2413x; 1.2413x over previous
//
#include <hip/hip_runtime.h>
#include <math.h>

// Problem constants: z [4,32,32,32] f32, embedding [32768,32] f32.
constexpr int Bc   = 4;
constexpr int Dc   = 32;
constexpr int HWc  = 1024;
constexpr int NE   = 32768;
constexpr int POS  = Bc * HWc;        // 4096 positions

constexpr int CCODES = 256;           // codes per chunk (32 KB hi+lo in LDS)
constexpr int NCHUNK = NE / CCODES;   // 128
constexpr int PPB    = 256;           // positions per phase-A block (8 waves)
constexpr int NPBLK  = POS / PPB;     // 16

// Filter tolerance: |hi-only - exact| <= 2^-10 * Sum|z||e| ~ 0.05 worst-case;
// 0.25 gives 5x margin (2*delta needed).
#define FILTER_TOL 0.25f

typedef _Float16 f16x8 __attribute__((ext_vector_type(8)));
typedef float    f32x4 __attribute__((ext_vector_type(4)));
typedef unsigned long long u64;

// Monotonic float<->uint order-preserving encode; pack with ~idx so equal
// values -> smaller index wins under max (jnp.argmax first-index rule).
__device__ inline unsigned encF(float v) {
    unsigned u = __float_as_uint(v);
    return (u & 0x80000000u) ? ~u : (u | 0x80000000u);
}
__device__ inline float decF(unsigned e) {
    unsigned u = (e & 0x80000000u) ? (e & 0x7fffffffu) : ~e;
    return __uint_as_float(u);
}
__device__ inline u64 packVI(float v, int idx) {
    return ((u64)encF(v) << 32) | (unsigned)(~idx);
}

// Prep: split-fp16. Blocks 0..127: emb -> Es [32768][64] (hi 0..31, lo
// 32..63; hi+lo = x to ~2^-22). Blocks 128..143: z -> Zs [4096][64], zero
// best (u32) and best2 (u64).
__global__ __launch_bounds__(256) void vq_eprep(
    const float* __restrict__ emb, const float* __restrict__ z,
    _Float16* __restrict__ Es, _Float16* __restrict__ Zs,
    unsigned* __restrict__ best, u64* __restrict__ best2)
{
    float x[Dc];
    _Float16* dptr;
    if (blockIdx.x < NE / 256) {
        const int c = blockIdx.x * 256 + threadIdx.x;
        const float4* src = reinterpret_cast<const float4*>(emb + (size_t)c * Dc);
#pragma unroll
        for (int q = 0; q < 8; ++q) {
            const float4 v = src[q];
            x[4*q+0] = v.x; x[4*q+1] = v.y; x[4*q+2] = v.z; x[4*q+3] = v.w;
        }
        dptr = Es + (size_t)c * 64;
    } else {
        const int p = (blockIdx.x - NE / 256) * 256 + threadIdx.x;
        best[p]  = 0u;     // below any encoded real
        best2[p] = 0ULL;
        const int b = p >> 10, hw = p & (HWc - 1);
        const float* zp = z + (size_t)b * Dc * HWc + hw;
#pragma unroll
        for (int d = 0; d < Dc; ++d) x[d] = zp[(size_t)d * HWc];
        dptr = Zs + (size_t)p * 64;
    }
    f16x8* dst = reinterpret_cast<f16x8*>(dptr);
#pragma unroll
    for (int q = 0; q < 4; ++q) {
        f16x8 h, l;
#pragma unroll
        for (int r = 0; r < 8; ++r) {
            const float xv = x[8*q+r];
            const _Float16 hv = (_Float16)xv;
            h[r] = hv;
            l[r] = (_Float16)(xv - (float)hv);
        }
        dst[q]     = h;
        dst[4 + q] = l;
    }
}

// Phase A: APPROX filter pass -- hi*hi MFMA only (1/3 the matrix work),
// value-only max3 epilogue (0.5 VALU/logit). Writes encoded per-(chunk,pos)
// max + global approx best. Staging identical to r14 (512-thread, proven).
__global__ __launch_bounds__(512)
__attribute__((amdgpu_waves_per_eu(4, 8)))
void vq_phaseA(
    const _Float16* __restrict__ Zs, const _Float16* __restrict__ Es,
    unsigned* __restrict__ chunkmaxE, unsigned* __restrict__ best)
{
    __shared__ __align__(16) char lds[CCODES * 128];   // 32 KB

    const int lin  = blockIdx.x;               // 0..2047
    const int xcd  = lin & 7;
    const int j    = lin >> 3;
    const int chunk = xcd * (NCHUNK / 8) + (j & (NCHUNK / 8 - 1));
    const int pblk  = j >> 4;                  // 0..15
    const int tid  = threadIdx.x;
    const int wave = tid >> 6, lane = tid & 63;
    const int m = lane & 15, g = lane >> 4;

    // stage chunk (hi+lo rows) -> LDS, pre-swizzled source (r14 pattern)
    {
        const char* src = (const char*)(Es + (size_t)chunk * CCODES * 64);
        char* dstbase = lds + wave * 1024;
#pragma unroll
        for (int r = 0; r < 4; ++r) {
            const int o    = r * 512 + tid;
            const int row  = o >> 3;
            const int ccol = o & 7;
            const int soff = row * 128 + ((ccol ^ (row & 7)) << 4);
            __builtin_amdgcn_global_load_lds(
                (const __attribute__((address_space(1))) void*)(src + soff),
                (__attribute__((address_space(3))) void*)(dstbase + r * 8192),
                16, 0, 0);
        }
    }

    const int posBase0 = pblk * PPB;
    const int posBase  = posBase0 + wave * 32;
    f16x8 Ahi[2];
#pragma unroll
    for (int t = 0; t < 2; ++t)
        Ahi[t] = *reinterpret_cast<const f16x8*>(
            Zs + (size_t)(posBase + t * 16 + m) * 64 + 8 * g);
#pragma unroll
    for (int t = 0; t < 2; ++t) asm volatile("" : "+v"(Ahi[t]));

    f32x4 zacc = {0.f, 0.f, 0.f, 0.f};
    asm volatile("" : "+v"(zacc));

    float bval[8];
#pragma unroll
    for (int i = 0; i < 8; ++i) bval[i] = -INFINITY;

    __syncthreads();

    const char* lbase = lds;
    const int off_h = m * 128 + ((g ^ (m & 7)) << 4);

#pragma unroll 2
    for (int ct = 0; ct < CCODES / 16; ct += 2) {      // tile pairs, hi only
        const char* p0 = lbase + ct * 2048;
        const f16x8 Bh0 = *reinterpret_cast<const f16x8*>(p0 + off_h);
        const f16x8 Bh1 = *reinterpret_cast<const f16x8*>(p0 + 2048 + off_h);
#pragma unroll
        for (int t = 0; t < 2; ++t) {
            const f32x4 aA = __builtin_amdgcn_mfma_f32_16x16x32_f16(Ahi[t], Bh0, zacc, 0, 0, 0);
            const f32x4 aB = __builtin_amdgcn_mfma_f32_16x16x32_f16(Ahi[t], Bh1, zacc, 0, 0, 0);
#pragma unroll
            for (int r = 0; r < 4; ++r)
                bval[t*4+r] = fmaxf(fmaxf(bval[t*4+r], aA[r]), aB[r]);
        }
    }

    // tail: value-only reduce across the 16 cols of each position
    __syncthreads();
    float* red = reinterpret_cast<float*>(lds);        // [256][17] f32
#pragma unroll
    for (int i = 0; i < 8; ++i) {
        const int t = i >> 2, r = i & 3;
        const int row = wave * 32 + t * 16 + 4 * g + r;
        red[row * 17 + m] = bval[i];
    }
    __syncthreads();
    if (tid < PPB) {
        float mx = red[tid * 17];
#pragma unroll
        for (int mm = 1; mm < 16; ++mm) mx = fmaxf(mx, red[tid * 17 + mm]);
        const unsigned e = encF(mx);
        chunkmaxE[(size_t)chunk * POS + posBase0 + tid] = e;
        atomicMax(best + posBase0 + tid, e);
    }
}

// Phase B: exact index recovery with LOCALITY. Block = (chunk, group of 16
// pos-tiles). Stage the chunk's B (hi+lo) into LDS once; each wave
// ballot-checks 4 tiles (64 coalesced positions) against best-tol and scans
// only qualifying tiles (~15%) with the exact 3-product + full tracking.
// Commit via packed u64 atomicMax (reduce/commit logic field-proven in r15).
__global__ __launch_bounds__(256) void vq_phaseB(
    const _Float16* __restrict__ Zs, const _Float16* __restrict__ Es,
    const unsigned* __restrict__ chunkmaxE, const unsigned* __restrict__ best,
    u64* __restrict__ best2)
{
    __shared__ __align__(16) char lds[CCODES * 128];   // 32 KB

    const int bid = blockIdx.x;                // 0..2047
    const int c   = bid >> 4;                  // chunk
    const int G   = bid & 15;                  // positions [G*256, G*256+256)
    const int tid = threadIdx.x;
    const int wave = tid >> 6, lane = tid & 63;
    const int m = lane & 15, g = lane >> 4;

    // stage chunk -> LDS (256-thread 8-pass variant, r10-proven)
    {
        const char* src = (const char*)(Es + (size_t)c * CCODES * 64);
        char* dstbase = lds + wave * 1024;
#pragma unroll
        for (int r = 0; r < 8; ++r) {
            const int o    = r * 256 + tid;
            const int row  = o >> 3;
            const int ccol = o & 7;
            const int soff = row * 128 + ((ccol ^ (row & 7)) << 4);
            __builtin_amdgcn_global_load_lds(
                (const __attribute__((address_space(1))) void*)(src + soff),
                (__attribute__((address_space(3))) void*)(dstbase + r * 4096),
                16, 0, 0);
        }
    }

    // candidate check (independent of LDS; overlaps staging)
    const int posW = G * 256 + wave * 64;      // this wave's 64 positions
    const unsigned cm = chunkmaxE[(size_t)c * POS + posW + lane];
    const unsigned bv = best[posW + lane];
    const unsigned thr = encF(decF(bv) - FILTER_TOL);
    const u64 bal = __ballot(cm >= thr);

    __syncthreads();   // staging complete

    const f32x4 zacc = {0.f, 0.f, 0.f, 0.f};
    const int cbase = c * CCODES;
    const int off_h = m * 128 + (( g      ^ (m & 7)) << 4);
    const int off_l = m * 128 + (((g + 4) ^ (m & 7)) << 4);

#pragma unroll 1
    for (int tl = 0; tl < 4; ++tl) {
        if (((bal >> (16 * tl)) & 0xFFFFULL) == 0ULL) continue;  // wave-uniform
        const int tt = (posW >> 4) + tl;       // global pos-tile id

        const _Float16* zrow = Zs + (size_t)(tt * 16 + m) * 64 + 8 * g;
        const f16x8 Ahi = *reinterpret_cast<const f16x8*>(zrow);
        const f16x8 Alo = *reinterpret_cast<const f16x8*>(zrow + 32);

        float bvalr[4];
        int   bct[4];
#pragma unroll
        for (int r = 0; r < 4; ++r) { bvalr[r] = -INFINITY; bct[r] = 0; }

#pragma unroll 2
        for (int ct = 0; ct < CCODES / 16; ++ct) {
            const f16x8 Bh = *reinterpret_cast<const f16x8*>(lds + ct * 2048 + off_h);
            const f16x8 Bl = *reinterpret_cast<const f16x8*>(lds + ct * 2048 + off_l);
            f32x4 acc;
            acc = __builtin_amdgcn_mfma_f32_16x16x32_f16(Ahi, Bh, zacc, 0, 0, 0);
            acc = __builtin_amdgcn_mfma_f32_16x16x32_f16(Ahi, Bl, acc,  0, 0, 0);
            acc = __builtin_amdgcn_mfma_f32_16x16x32_f16(Alo, Bh, acc,  0, 0, 0);
#pragma unroll
            for (int r = 0; r < 4; ++r) {
                const bool up = acc[r] > bvalr[r];   // strict '>': first tile
                bct[r]   = up ? ct : bct[r];
                bvalr[r] = fmaxf(bvalr[r], acc[r]);
            }
        }

        u64 pk[4];
#pragma unroll
        for (int r = 0; r < 4; ++r)
            pk[r] = packVI(bvalr[r], cbase + bct[r] * 16 + m);
#pragma unroll
        for (int s = 1; s < 16; s <<= 1) {
#pragma unroll
            for (int r = 0; r < 4; ++r) {
                const u64 o = __shfl_xor(pk[r], s, 64);
                if (o > pk[r]) pk[r] = o;
            }
        }
        u64 mine = pk[0];
        if (m == 1) mine = pk[1];
        if (m == 2) mine = pk[2];
        if (m == 3) mine = pk[3];
        if (m < 4) atomicMax(best2 + tt * 16 + 4 * g + m, mine);
    }
}

// Finish: decode winner, gather embedding row, write z_q coalesced + index.
__global__ __launch_bounds__(256) void vq_finish_kernel(
    const u64* __restrict__ best2, const float* __restrict__ emb,
    float* __restrict__ zq, float* __restrict__ indOut)
{
    const int p = blockIdx.x * 256 + threadIdx.x;
    const u64 pk = best2[p];
    const int idx = (int)(~(unsigned)pk);

    const float4* e = reinterpret_cast<const float4*>(emb + (size_t)idx * Dc);
    const int b  = p >> 10;
    const int hw = p & (HWc - 1);
    float* o = zq + (size_t)b * Dc * HWc + hw;
#pragma unroll
    for (int q = 0; q < 8; ++q) {
        const float4 v = e[q];
        o[(size_t)(4*q+0) * HWc] = v.x;
        o[(size_t)(4*q+1) * HWc] = v.y;
        o[(size_t)(4*q+2) * HWc] = v.z;
        o[(size_t)(4*q+3) * HWc] = v.w;
    }
    indOut[p] = (float)idx;
}

extern "C" void kernel_launch(void* const* d_in, const int* in_sizes, int n_in,
                              void* d_out, int out_size, void* d_ws, size_t ws_size,
                              hipStream_t stream)
{
    const float* z   = (const float*)d_in[0];
    const float* emb = (const float*)d_in[1];

    float* out    = (float*)d_out;
    float* zq     = out;
    float* indOut = out + (size_t)Bc * Dc * HWc;

    char* w = (char*)d_ws;
    u64*      best2     = (u64*)w;              w += (size_t)POS * 8;
    unsigned* best      = (unsigned*)w;         w += (size_t)POS * 4;
    unsigned* chunkmaxE = (unsigned*)w;         w += (size_t)NCHUNK * POS * 4;
    _Float16* Es        = (_Float16*)w;         w += (size_t)NE * 64 * 2;
    _Float16* Zs        = (_Float16*)w;

    hipLaunchKernelGGL(vq_eprep, dim3(NE / 256 + POS / 256), dim3(256), 0,
                       stream, emb, z, Es, Zs, best, best2);
    hipLaunchKernelGGL(vq_phaseA, dim3(NCHUNK * NPBLK), dim3(512), 0, stream,
                       Zs, Es, chunkmaxE, best);
    hipLaunchKernelGGL(vq_phaseB, dim3(NCHUNK * 16), dim3(256), 0, stream,
                       Zs, Es, chunkmaxE, best, best2);
    hipLaunchKernelGGL(vq_finish_kernel, dim3(POS / 256), dim3(256), 0, stream,
                       best2, emb, zq, indOut);
}

// Round 17
// 40.991 us; speedup vs baseline: 1.5308x; 1.2332x over previous
//
#include <hip/hip_runtime.h>
#include <math.h>

// Problem constants: z [4,32,32,32] f32, embedding [32768,32] f32.
constexpr int Bc   = 4;
constexpr int Dc   = 32;
constexpr int HWc  = 1024;
constexpr int NE   = 32768;
constexpr int POS  = Bc * HWc;        // 4096 positions

constexpr int CCODES = 256;           // codes per chunk (32 KB hi+lo in LDS)
constexpr int NCHUNK = NE / CCODES;   // 128
constexpr int PPB    = 256;           // positions per phase-A block (8 waves)
constexpr int NPBLK  = POS / PPB;     // 16

typedef _Float16 f16x8 __attribute__((ext_vector_type(8)));
typedef float    f32x4 __attribute__((ext_vector_type(4)));
typedef unsigned long long u64;

// Monotonic float->uint order-preserving encode; pack with ~k so equal
// values -> smaller k wins under max (jnp.argmax first-index rule).
__device__ inline unsigned encF(float v) {
    unsigned u = __float_as_uint(v);
    return (u & 0x80000000u) ? ~u : (u | 0x80000000u);
}
__device__ inline u64 packVK(float v, int k) {
    return ((u64)encF(v) << 32) | (unsigned)(~k);
}

// Prep: split-fp16. Blocks 0..127: emb -> Es [32768][64] (hi 0..31, lo
// 32..63; hi+lo = x to ~2^-22). Blocks 128..143: z -> Zs [4096][64] and
// zero best2.
__global__ __launch_bounds__(256) void vq_eprep(
    const float* __restrict__ emb, const float* __restrict__ z,
    _Float16* __restrict__ Es, _Float16* __restrict__ Zs,
    u64* __restrict__ best2)
{
    float x[Dc];
    _Float16* dptr;
    if (blockIdx.x < NE / 256) {
        const int c = blockIdx.x * 256 + threadIdx.x;
        const float4* src = reinterpret_cast<const float4*>(emb + (size_t)c * Dc);
#pragma unroll
        for (int q = 0; q < 8; ++q) {
            const float4 v = src[q];
            x[4*q+0] = v.x; x[4*q+1] = v.y; x[4*q+2] = v.z; x[4*q+3] = v.w;
        }
        dptr = Es + (size_t)c * 64;
    } else {
        const int p = (blockIdx.x - NE / 256) * 256 + threadIdx.x;
        best2[p] = 0ULL;   // below any encoded real
        const int b = p >> 10, hw = p & (HWc - 1);
        const float* zp = z + (size_t)b * Dc * HWc + hw;
#pragma unroll
        for (int d = 0; d < Dc; ++d) x[d] = zp[(size_t)d * HWc];
        dptr = Zs + (size_t)p * 64;
    }
    f16x8* dst = reinterpret_cast<f16x8*>(dptr);
#pragma unroll
    for (int q = 0; q < 4; ++q) {
        f16x8 h, l;
#pragma unroll
        for (int r = 0; r < 8; ++r) {
            const float xv = x[8*q+r];
            const _Float16 hv = (_Float16)xv;
            h[r] = hv;
            l[r] = (_Float16)(xv - (float)hv);
        }
        dst[q]     = h;
        dst[4 + q] = l;
    }
}

// Phase A: EXACT split-fp16 MFMA (hi*hi + hi*lo + lo*hi; bit-proven absmax 0
// since r8), but VALUE-ONLY tracking: epilogue is one fused max3 per acc
// slot per tile-pair (64 VALU/wave vs r14's 384 cmp/cndmask/max). Tail packs
// (encVal, ~chunk) -> u64 atomicMax best2[pos]: value + winning chunk with
// first-chunk tie-break. No per-(chunk,pos) array, no index tracking here.
// Staging + swizzle identical to r10-r16 (measured 0 conflicts).
__global__ __launch_bounds__(512)
__attribute__((amdgpu_waves_per_eu(4, 8)))
void vq_phaseA(
    const _Float16* __restrict__ Zs, const _Float16* __restrict__ Es,
    u64* __restrict__ best2)
{
    __shared__ __align__(16) char lds[CCODES * 128];   // 32 KB

    const int lin  = blockIdx.x;               // 0..2047
    const int xcd  = lin & 7;
    const int j    = lin >> 3;
    const int chunk = xcd * (NCHUNK / 8) + (j & (NCHUNK / 8 - 1));
    const int pblk  = j >> 4;                  // 0..15
    const int tid  = threadIdx.x;
    const int wave = tid >> 6, lane = tid & 63;
    const int m = lane & 15, g = lane >> 4;

    // stage chunk (hi+lo rows) -> LDS, pre-swizzled source
    {
        const char* src = (const char*)(Es + (size_t)chunk * CCODES * 64);
        char* dstbase = lds + wave * 1024;
#pragma unroll
        for (int r = 0; r < 4; ++r) {
            const int o    = r * 512 + tid;
            const int row  = o >> 3;
            const int ccol = o & 7;
            const int soff = row * 128 + ((ccol ^ (row & 7)) << 4);
            __builtin_amdgcn_global_load_lds(
                (const __attribute__((address_space(1))) void*)(src + soff),
                (__attribute__((address_space(3))) void*)(dstbase + r * 8192),
                16, 0, 0);
        }
    }

    const int posBase0 = pblk * PPB;
    const int posBase  = posBase0 + wave * 32;
    f16x8 Ahi[2], Alo[2];
#pragma unroll
    for (int t = 0; t < 2; ++t) {
        const _Float16* zrow = Zs + (size_t)(posBase + t * 16 + m) * 64 + 8 * g;
        Ahi[t] = *reinterpret_cast<const f16x8*>(zrow);
        Alo[t] = *reinterpret_cast<const f16x8*>(zrow + 32);
    }
#pragma unroll
    for (int t = 0; t < 2; ++t) asm volatile("" : "+v"(Ahi[t]), "+v"(Alo[t]));

    f32x4 zacc = {0.f, 0.f, 0.f, 0.f};
    asm volatile("" : "+v"(zacc));

    float bval[8];
#pragma unroll
    for (int i = 0; i < 8; ++i) bval[i] = -INFINITY;

    __syncthreads();

    const char* lbase = lds;
    const int off_h = m * 128 + (( g      ^ (m & 7)) << 4);
    const int off_l = m * 128 + (((g + 4) ^ (m & 7)) << 4);

#pragma unroll 2
    for (int ct = 0; ct < CCODES / 16; ct += 2) {      // tile pairs
        const char* p0 = lbase + ct * 2048;
        const f16x8 Bh0 = *reinterpret_cast<const f16x8*>(p0 + off_h);
        const f16x8 Bl0 = *reinterpret_cast<const f16x8*>(p0 + off_l);
        const f16x8 Bh1 = *reinterpret_cast<const f16x8*>(p0 + 2048 + off_h);
        const f16x8 Bl1 = *reinterpret_cast<const f16x8*>(p0 + 2048 + off_l);

#pragma unroll
        for (int t = 0; t < 2; ++t) {
            f32x4 aA, aB;      // two independent exact 3-product chains
            aA = __builtin_amdgcn_mfma_f32_16x16x32_f16(Ahi[t], Bh0, zacc, 0, 0, 0);
            aB = __builtin_amdgcn_mfma_f32_16x16x32_f16(Ahi[t], Bh1, zacc, 0, 0, 0);
            aA = __builtin_amdgcn_mfma_f32_16x16x32_f16(Ahi[t], Bl0, aA,  0, 0, 0);
            aB = __builtin_amdgcn_mfma_f32_16x16x32_f16(Ahi[t], Bl1, aB,  0, 0, 0);
            aA = __builtin_amdgcn_mfma_f32_16x16x32_f16(Alo[t], Bh0, aA,  0, 0, 0);
            aB = __builtin_amdgcn_mfma_f32_16x16x32_f16(Alo[t], Bh1, aB,  0, 0, 0);
#pragma unroll
            for (int r = 0; r < 4; ++r)
                bval[t*4+r] = fmaxf(fmaxf(bval[t*4+r], aA[r]), aB[r]);  // max3
        }
    }

    // tail: value-only LDS reduce, then (val, ~chunk) u64 atomic per position
    __syncthreads();
    float* red = reinterpret_cast<float*>(lds);        // [256][17] f32
#pragma unroll
    for (int i = 0; i < 8; ++i) {
        const int t = i >> 2, r = i & 3;
        const int row = wave * 32 + t * 16 + 4 * g + r;
        red[row * 17 + m] = bval[i];
    }
    __syncthreads();
    if (tid < PPB) {
        float mx = red[tid * 17];
#pragma unroll
        for (int mm = 1; mm < 16; ++mm) mx = fmaxf(mx, red[tid * 17 + mm]);
        atomicMax(best2 + posBase0 + tid, packVK(mx, chunk));
    }
}

// Phase B: one wave per position. Decode winning chunk, rescan its 256 codes
// with scalar fp32 dots: 8-lane group per code (float4 loads fully coalesced,
// 1 KB/sweep), shuffle-reduce the 4-dim partials, track (val,idx) per lane,
// packed-u64 butterfly across groups, then lanes 0..31 gather e[idx] and
// write z_q + ind directly (no finish kernel). Only 4096 waves x 256 codes
// = 0.8% of phase A's logit work, exact fp32.
__global__ __launch_bounds__(256) void vq_phaseB(
    const float* __restrict__ z, const float* __restrict__ emb,
    const u64* __restrict__ best2, float* __restrict__ zq,
    float* __restrict__ indOut)
{
    const int p    = blockIdx.x * 4 + (threadIdx.x >> 6);   // 0..4095
    const int lane = threadIdx.x & 63;

    const int chunk = (int)(~(unsigned)best2[p]) & (NCHUNK - 1);
    const int cbase = chunk * CCODES;
    const int b = p >> 10, hw = p & (HWc - 1);

    // this lane's 4 dims of z[p]
    const int d0 = (lane & 7) * 4;
    const float* zp = z + (size_t)b * Dc * HWc + hw;
    const float z0 = zp[(size_t)(d0 + 0) * HWc];
    const float z1 = zp[(size_t)(d0 + 1) * HWc];
    const float z2 = zp[(size_t)(d0 + 2) * HWc];
    const float z3 = zp[(size_t)(d0 + 3) * HWc];

    const float4* eb = reinterpret_cast<const float4*>(emb + (size_t)cbase * Dc);

    float bv = -INFINITY;
    int   bi = cbase;
#pragma unroll 4
    for (int s = 0; s < 32; ++s) {                 // 8 codes per sweep
        const float4 ev = eb[s * 64 + lane];
        float d = z0 * ev.x + z1 * ev.y;
        d = fmaf(z2, ev.z, d);
        d = fmaf(z3, ev.w, d);
        d += __shfl_xor(d, 1, 64);                 // reduce 8-lane group
        d += __shfl_xor(d, 2, 64);
        d += __shfl_xor(d, 4, 64);
        const int code = cbase + s * 8 + (lane >> 3);
        const bool up = d > bv;                    // ascending s: first idx
        bi = up ? code : bi;
        bv = fmaxf(bv, d);
    }

    // cross-group merge: packed (encVal, ~idx), butterfly over bits 3..5
    u64 pk = packVK(bv, bi);
#pragma unroll
    for (int s = 8; s < 64; s <<= 1) {
        const u64 o = __shfl_xor(pk, s, 64);
        if (o > pk) pk = o;
    }
    const int widx = (int)(~(unsigned)pk);

    // fused output: gather winning row (coalesced 128 B), write z_q + ind
    if (lane < Dc) {
        const float ev = emb[(size_t)widx * Dc + lane];
        zq[(size_t)b * Dc * HWc + (size_t)lane * HWc + hw] = ev;
    }
    if (lane == 0) indOut[p] = (float)widx;        // <=32767: exact in fp32
}

// Fallback (ws too small): scalar VALU scan + finish.
__global__ __launch_bounds__(256, 4) void vq_scalar(
    const float* __restrict__ z, const float* __restrict__ emb,
    u64* __restrict__ best)
{
    const int lin = blockIdx.x;
    const int xcd = lin & 7, j = lin >> 3;
    const int seg    = xcd * 32 + (j & 31);
    const int posgrp = j >> 5;

    const int t  = posgrp * 256 + threadIdx.x;
    const int p0 = t, p1 = t + POS / 2;
    const int b0 = p0 >> 10, hw0 = p0 & (HWc - 1);
    const int b1 = p1 >> 10, hw1 = p1 & (HWc - 1);
    const float* zp0 = z + (size_t)b0 * Dc * HWc + hw0;
    const float* zp1 = z + (size_t)b1 * Dc * HWc + hw1;

    float za[Dc], zb[Dc];
#pragma unroll
    for (int d = 0; d < Dc; ++d) {
        za[d] = zp0[(size_t)d * HWc];
        zb[d] = zp1[(size_t)d * HWc];
    }
#pragma unroll
    for (int d = 0; d < Dc; ++d) asm volatile("" : "+v"(za[d]), "+v"(zb[d]));

    const int c0 = seg * 128;
    const float4* e4 = reinterpret_cast<const float4*>(emb + (size_t)c0 * Dc);
    float v0 = -INFINITY, v1 = -INFINITY;
    int   i0 = c0, i1 = c0;
#pragma unroll 1
    for (int cc = 0; cc < 128; ++cc, e4 += 8) {
        float a0 = 0.f, a1 = 0.f;
#pragma unroll
        for (int q = 0; q < 8; ++q) {
            const float4 e = e4[q];
            a0 = fmaf(za[4*q+0], e.x, a0); a1 = fmaf(zb[4*q+0], e.x, a1);
            a0 = fmaf(za[4*q+1], e.y, a0); a1 = fmaf(zb[4*q+1], e.y, a1);
            a0 = fmaf(za[4*q+2], e.z, a0); a1 = fmaf(zb[4*q+2], e.z, a1);
            a0 = fmaf(za[4*q+3], e.w, a0); a1 = fmaf(zb[4*q+3], e.w, a1);
        }
        const int c = c0 + cc;
        if (a0 > v0) { v0 = a0; i0 = c; }
        if (a1 > v1) { v1 = a1; i1 = c; }
    }
    atomicMax(best + p0, packVK(v0, i0));
    atomicMax(best + p1, packVK(v1, i1));
}

__global__ __launch_bounds__(256) void vq_finish_kernel(
    const u64* __restrict__ best, const float* __restrict__ emb,
    float* __restrict__ zq, float* __restrict__ indOut)
{
    const int p = blockIdx.x * 256 + threadIdx.x;
    const int idx = (int)(~(unsigned)best[p]);

    const float4* e = reinterpret_cast<const float4*>(emb + (size_t)idx * Dc);
    const int b  = p >> 10;
    const int hw = p & (HWc - 1);
    float* o = zq + (size_t)b * Dc * HWc + hw;
#pragma unroll
    for (int q = 0; q < 8; ++q) {
        const float4 v = e[q];
        o[(size_t)(4*q+0) * HWc] = v.x;
        o[(size_t)(4*q+1) * HWc] = v.y;
        o[(size_t)(4*q+2) * HWc] = v.z;
        o[(size_t)(4*q+3) * HWc] = v.w;
    }
    indOut[p] = (float)idx;
}

extern "C" void kernel_launch(void* const* d_in, const int* in_sizes, int n_in,
                              void* d_out, int out_size, void* d_ws, size_t ws_size,
                              hipStream_t stream)
{
    const float* z   = (const float*)d_in[0];
    const float* emb = (const float*)d_in[1];

    float* out    = (float*)d_out;
    float* zq     = out;
    float* indOut = out + (size_t)Bc * Dc * HWc;

    char* w = (char*)d_ws;
    u64*      best2 = (u64*)w;          w += (size_t)POS * 8;
    _Float16* Es    = (_Float16*)w;     w += (size_t)NE * 64 * 2;
    _Float16* Zs    = (_Float16*)w;
    const size_t needed = (size_t)POS * 8 + (size_t)(NE + POS) * 64 * 2;

    if (ws_size >= needed) {
        hipLaunchKernelGGL(vq_eprep, dim3(NE / 256 + POS / 256), dim3(256), 0,
                           stream, emb, z, Es, Zs, best2);
        hipLaunchKernelGGL(vq_phaseA, dim3(NCHUNK * NPBLK), dim3(512), 0,
                           stream, Zs, Es, best2);
        hipLaunchKernelGGL(vq_phaseB, dim3(POS / 4), dim3(256), 0, stream,
                           z, emb, best2, zq, indOut);
    } else {
        hipMemsetAsync(best2, 0, (size_t)POS * sizeof(u64), stream);
        hipLaunchKernelGGL(vq_scalar, dim3(2048), dim3(256), 0, stream,
                           z, emb, best2);
        hipLaunchKernelGGL(vq_finish_kernel, dim3(POS / 256), dim3(256), 0,
                           stream, best2, emb, zq, indOut);
    }
}